// Round 1
// baseline (127.323 us; speedup 1.0000x reference)
//
#include <hip/hip_runtime.h>
#include <hip/hip_bf16.h>

// R13: barrier-elimination + G-tail prefetch, building on R12's store-based
// grid barrier (measured 44.0-47.6us kernel, 115.3 dur).
// Counters showed no-regime (VALU 4.5%, HBM 1.5%, occ 4.2%): pure latency
// chain of 4 barriers + phase-serial scattered loads. Two structural changes:
//  (1) TRANSPOSED LOGITS: each block owns 8 key samples; it computes those
//      samples' contribution to ALL 100 logits via keys COLUMNS (6 float4
//      per thread, prefetched at entry) and stores a 100-float partial row.
//      After ONE barrier, every block reduces the 128x100 partials
//      (coalesced) + softmax locally. Eliminates bar1/bar3 (4->2 barriers)
//      and the key1/key2 global round-trips entirely.
//  (2) G PREFETCH + FULL-BLOCK SPLIT: all of G's input taps have
//      entry-computable addresses -> prefetched into 24 regs/thread at
//      entry (latency hidden under A-F). G split across both 128-thread
//      halves (l in {0,1} vs {2,3}), combined via LDS. G = pure VALU/LDS.
// Structure (validated R1-R12): looper == sigmoid(3.0) exactly -> exactly two
// long_conv applications; lc_* inputs unused. Phases:
//   A: per-block key1 samples (LDS bcast) + partial logits -> plog1
//   bar1
//   C': reduce plog1 -> softmax -> kern1 -> w_eff       [REPLICATED]
//   D: key2 samples via w_eff + partial logits -> plog2
//   bar2
//   F': reduce plog2 -> softmax -> kern2 -> composite 13x13 tables
//   G: out = sigmoid(composite convT), prefetched taps, 256-thread split
// Ledger (measured): agent acquire/release fences forbidden (R4); cross-block
// data sc1 relaxed-agent only; sc1 store->load visibility validated (R8); no
// dynamic-indexed register arrays (R7 spill); no rolled global-load loops
// (R11); entry prefetch of all static loads (R12 win). Deadlock safety:
// 128 blocks x 256 thr, launch_bounds(256,1), ~12.5KB LDS -> co-resident.
// Barrier state (2 x 1KB) zeroed by captured memset node each call.

#define GRID 128

#define LD1(p)     __hip_atomic_load((p), __ATOMIC_RELAXED, __HIP_MEMORY_SCOPE_AGENT)
#define ST1(p, v)  __hip_atomic_store((p), (v), __ATOMIC_RELAXED, __HIP_MEMORY_SCOPE_AGENT)

__device__ __forceinline__ float sigmoidf_(float z) {
    return 1.0f / (1.0f + expf(-z));
}

// base: 256 words (1KB). arrival[0..127]; release flag at word 160.
// No atomics anywhere: stores + loads only. (R12-validated)
__device__ __forceinline__ void gbar(unsigned* base, int blk, int t) {
    asm volatile("s_waitcnt vmcnt(0)" ::: "memory");   // data sc1 stores visible
    __syncthreads();
    if (t == 0) ST1(base + blk, 1u);                   // arrival store, own word
    if (blk == 0) {
        if (t < 128) {                                 // 2 waves poll 128 words
            while (LD1(base + t) == 0u)
                __builtin_amdgcn_s_sleep(8);
        }
        __syncthreads();
        if (t == 0) ST1(base + 160, 1u);               // release flag, own line
    } else {
        if (t == 0) {
            while (LD1(base + 160) == 0u)
                __builtin_amdgcn_s_sleep(8);
        }
        __syncthreads();
    }
    asm volatile("" ::: "memory");
    __syncthreads();
}

// entry tap loads for one key stage (2 samples/wave; sample = blk*4+wv+rep*512)
__device__ __forceinline__ void key_prefetch(const float* __restrict__ in,
                                             int mul, int dbl, int blk,
                                             int lane, int wv,
                                             float xa[2], float xb[2]) {
#pragma unroll
    for (int rep = 0; rep < 2; ++rep) {
        int s = blk * 4 + wv + rep * 512;
        int ii = s >> 5, jj = s & 31;
        int qy = (ii * mul) >> 5, qx = (jj * mul) >> 5;
        int by = dbl ? 2 * qy : qy - 1;
        int bx = dbl ? 2 * qx : qx - 1;
        {
            int l = lane;                    // < 64 < 75: always a valid tap
            int ci = l / 25, rm = l % 25, r = rm / 5, cc = rm % 5;
            int y = by + r, x = bx + cc;
            xa[rep] = ((unsigned)y < 1024u && (unsigned)x < 1024u)
                      ? 2.0f * in[ci * 1048576 + y * 1024 + x] - 1.0f : 0.f;
        }
        xb[rep] = 0.f;
        if (lane < 11) {
            int l = lane + 64;
            int ci = l / 25, rm = l % 25, r = rm / 5, cc = rm % 5;
            int y = by + r, x = bx + cc;
            xb[rep] = ((unsigned)y < 1024u && (unsigned)x < 1024u)
                      ? 2.0f * in[ci * 1048576 + y * 1024 + x] - 1.0f : 0.f;
        }
    }
}

// key values from prefetched taps -> skv LDS (24 floats: [c*8 + rep*4 + wv])
__device__ __forceinline__ void key_stage(const float* __restrict__ sw,
                                          const float* __restrict__ sb,
                                          const float xa[2], const float xb[2],
                                          float* __restrict__ skv,
                                          int lane, int wv) {
#pragma unroll
    for (int rep = 0; rep < 2; ++rep) {
        float p0 = xa[rep] * sw[lane];
        float p1 = xa[rep] * sw[75 + lane];
        float p2 = xa[rep] * sw[150 + lane];
        if (lane < 11) {
            p0 += xb[rep] * sw[64 + lane];
            p1 += xb[rep] * sw[139 + lane];
            p2 += xb[rep] * sw[214 + lane];
        }
#pragma unroll
        for (int off = 32; off > 0; off >>= 1) {
            p0 += __shfl_xor(p0, off, 64);
            p1 += __shfl_xor(p1, off, 64);
            p2 += __shfl_xor(p2, off, 64);
        }
        if (lane == 0) {
            skv[0 * 8 + rep * 4 + wv] = sigmoidf_(p0 + sb[0]);
            skv[1 * 8 + rep * 4 + wv] = sigmoidf_(p1 + sb[1]);
            skv[2 * 8 + rep * 4 + wv] = sigmoidf_(p2 + sb[2]);
        }
    }
}

// softmax over slog[0..99] (LDS) -> satt (LDS); runs in every block
__device__ __forceinline__ void softmax_lds(const float* __restrict__ slog,
                                            float* __restrict__ satt,
                                            int lane, int wv) {
    if (wv == 0) {
        float v1 = slog[lane];
        float v2 = (lane + 64 < 100) ? slog[lane + 64] : -3.4e38f;
        float mx = fmaxf(v1, v2);
#pragma unroll
        for (int off = 32; off > 0; off >>= 1) mx = fmaxf(mx, __shfl_xor(mx, off, 64));
        float e1 = expf(v1 - mx);
        float e2 = (lane + 64 < 100) ? expf(v2 - mx) : 0.f;
        float s = e1 + e2;
#pragma unroll
        for (int off = 32; off > 0; off >>= 1) s += __shfl_xor(s, off, 64);
        float inv = 1.0f / s;
        satt[lane] = e1 * inv;
        if (lane + 64 < 100) satt[lane + 64] = e2 * inv;
    }
    __syncthreads();
}

__global__ __launch_bounds__(256, 1) void k_fused(
    const float* __restrict__ in, const float* __restrict__ cw,
    const float* __restrict__ cb, const float* __restrict__ keys,
    const float* __restrict__ vals, float* __restrict__ out,
    float* __restrict__ ws, unsigned* __restrict__ ctr)
{
    __shared__ float smem[3136];
    float* sk1  = smem;          // 225  kern1 (persists C'->F')
    float* sk2  = smem + 232;    // 225  kern2
    float* satt = smem + 464;    // 100  softmax
    float* sw   = smem + 568;    // 225  conv weights, then w_eff
    float* sb   = smem + 800;    // 3    bias
    float* sW   = smem + 808;    // 1521 composite W [(ci*3+o)*169 + e*13+f]
    float* sWy  = smem + 2332;   // 117
    float* sWx  = smem + 2452;   // 117
    float* sWxy = smem + 2572;   // 9
    float* skv  = smem + 2584;   // 24   block's key samples [c*8+rep*4+wv]
    float* slog = smem + 2608;   // 128  reduced logits
    float* sga  = smem + 2736;   // 384  G half-combine

    float* plog1 = ws;           // [128 blocks][128 stride], 100 used
    float* plog2 = ws + 16384;

    const int t = threadIdx.x, lane = t & 63, wv = t >> 6;
    const int blk = blockIdx.x;

    // ---- entry prefetch: everything with entry-computable addresses ----
    float xa1[2], xb1[2], xa2[2], xb2[2];
    key_prefetch(in, 510, 1, blk, lane, wv, xa1, xb1);
    key_prefetch(in, 1022, 0, blk, lane, wv, xa2, xb2);

    // keys columns for this block's 8 samples (serves BOTH logit stages)
    float4 k4[3][2];
    if (t < 100) {
        const float* kr = keys + t * 3072 + blk * 4;
#pragma unroll
        for (int c = 0; c < 3; ++c)
#pragma unroll
            for (int r = 0; r < 2; ++r)
                k4[c][r] = *reinterpret_cast<const float4*>(kr + c * 1024 + r * 512);
    } else {
#pragma unroll
        for (int c = 0; c < 3; ++c)
#pragma unroll
            for (int r = 0; r < 2; ++r)
                k4[c][r] = make_float4(0.f, 0.f, 0.f, 0.f);
    }

    // G geometry + tap prefetch (j = output col, h = which half of taps)
    const int j = t & 127, h = t >> 7;
    const int R = (blk * 4093) >> 7;
    const int C = (j * 4093) >> 7;
    const int ybase = (R + 6) >> 2, r0 = (R + 6) & 3, nk = (r0 == 0) ? 4 : 3;
    const int xbase = (C + 6) >> 2, f0 = (C + 6) & 3, nl = (f0 == 0) ? 4 : 3;
    float gx0[4][2], gx1[4][2], gx2[4][2];
#pragma unroll
    for (int k = 0; k < 4; ++k) {
        int iy = ybase - k;
#pragma unroll
        for (int lh = 0; lh < 2; ++lh) {
            int l = h * 2 + lh;
            int ix = xbase - l;
            bool ok = ((unsigned)iy < 1024u) && ((unsigned)ix < 1024u)
                      && (k < nk) && (l < nl);
            int off = iy * 1024 + ix;
            gx0[k][lh] = ok ? 2.0f * in[off] - 1.0f : 0.f;
            gx1[k][lh] = ok ? 2.0f * in[1048576 + off] - 1.0f : 0.f;
            gx2[k][lh] = ok ? 2.0f * in[2097152 + off] - 1.0f : 0.f;
        }
    }

    if (t < 225) sw[t] = cw[t];
    if (t < 3)   sb[t] = cb[t];
    __syncthreads();

    // ---- A: key1 samples + partial logits (all blocks) ----
    key_stage(sw, sb, xa1, xb1, skv, lane, wv);
    __syncthreads();
    if (t < 100) {
        float s = 0.f;
#pragma unroll
        for (int c = 0; c < 3; ++c)
#pragma unroll
            for (int r = 0; r < 2; ++r) {
                float4 kk = k4[c][r];
                const float* kv = skv + c * 8 + r * 4;
                s += kk.x * kv[0] + kk.y * kv[1] + kk.z * kv[2] + kk.w * kv[3];
            }
        ST1(plog1 + blk * 128 + t, s);
    }
    gbar(ctr, blk, t);

    // ---- C' (replicated): reduce partials -> softmax -> kern1 -> w_eff ----
    if (t < 100) {
        const float* p = plog1 + t;
        float s0 = 0.f, s1 = 0.f, s2 = 0.f, s3 = 0.f;
#pragma unroll
        for (int b = 0; b < 32; ++b) {
            s0 += LD1(p + (4 * b + 0) * 128);
            s1 += LD1(p + (4 * b + 1) * 128);
            s2 += LD1(p + (4 * b + 2) * 128);
            s3 += LD1(p + (4 * b + 3) * 128);
        }
        slog[t] = (s0 + s1) + (s2 + s3);
    }
    __syncthreads();
    softmax_lds(slog, satt, lane, wv);
    if (t < 225) {
        float s = 0.f;
#pragma unroll
        for (int n = 0; n < 100; ++n) s += vals[n * 225 + t] * satt[n];
        sk1[t] = s;
    }
    __syncthreads();
    if (t < 225) {   // w_eff[co][ci][a][bb] = conv(convT(.,kern1)) composite
        int co = t / 75, rem = t % 75, ci = rem / 25, a = (rem % 25) / 5, bb = rem % 5;
        float s = 0.f;
#pragma unroll
        for (int c = 0; c < 5; ++c) {
            int u = c + 2 * a - 4;
            if ((unsigned)u >= 5u) continue;
#pragma unroll
            for (int d = 0; d < 5; ++d) {
                int v = d + 2 * bb - 4;
                if ((unsigned)v >= 5u) continue;
#pragma unroll
                for (int cm = 0; cm < 3; ++cm)
                    s += sk1[ci * 75 + cm * 25 + c * 5 + d] * cw[co * 75 + cm * 25 + u * 5 + v];
            }
        }
        sw[t] = s;    // nobody reads old sw in this phase
    }
    __syncthreads();

    // ---- D: key2 samples via w_eff + partial logits ----
    key_stage(sw, sb, xa2, xb2, skv, lane, wv);
    __syncthreads();
    if (t < 100) {
        float s = 0.f;
#pragma unroll
        for (int c = 0; c < 3; ++c)
#pragma unroll
            for (int r = 0; r < 2; ++r) {
                float4 kk = k4[c][r];
                const float* kv = skv + c * 8 + r * 4;
                s += kk.x * kv[0] + kk.y * kv[1] + kk.z * kv[2] + kk.w * kv[3];
            }
        ST1(plog2 + blk * 128 + t, s);
    }
    gbar(ctr + 256, blk, t);

    // ---- F' (replicated): reduce -> softmax -> kern2 -> composite tables ----
    if (t < 100) {
        const float* p = plog2 + t;
        float s0 = 0.f, s1 = 0.f, s2 = 0.f, s3 = 0.f;
#pragma unroll
        for (int b = 0; b < 32; ++b) {
            s0 += LD1(p + (4 * b + 0) * 128);
            s1 += LD1(p + (4 * b + 1) * 128);
            s2 += LD1(p + (4 * b + 2) * 128);
            s3 += LD1(p + (4 * b + 3) * 128);
        }
        slog[t] = (s0 + s1) + (s2 + s3);
    }
    __syncthreads();
    softmax_lds(slog, satt, lane, wv);
    if (t < 225) {
        float s = 0.f;
#pragma unroll
        for (int n = 0; n < 100; ++n) s += vals[n * 225 + t] * satt[n];
        sk2[t] = s;
    }
    __syncthreads();
    for (int idx = t; idx < 1521; idx += 256) {   // W
        int ci = idx / 507, rem = idx % 507, o = rem / 169;
        int ef = rem % 169, e = ef / 13, f = ef % 13;
        float s = 0.f;
#pragma unroll
        for (int c = 0; c < 5; ++c) {
            int a = e - 2 * c;
            if ((unsigned)a >= 5u) continue;
#pragma unroll
            for (int d = 0; d < 5; ++d) {
                int b2 = f - 2 * d;
                if ((unsigned)b2 >= 5u) continue;
#pragma unroll
                for (int cm = 0; cm < 3; ++cm)
                    s += sk1[ci * 75 + cm * 25 + c * 5 + d] * sk2[cm * 75 + o * 25 + a * 5 + b2];
            }
        }
        sW[idx] = s;
    }
    if (t < 117) {   // Wy: phantom out1-row (c=1 -> oy1=-1), a=4
        int ci = t / 39, o = (t % 39) / 13, f = t % 13;
        float s = 0.f;
#pragma unroll
        for (int d = 0; d < 5; ++d) {
            int b2 = f - 2 * d;
            if ((unsigned)b2 >= 5u) continue;
#pragma unroll
            for (int cm = 0; cm < 3; ++cm)
                s += sk1[ci * 75 + cm * 25 + 5 + d] * sk2[cm * 75 + o * 25 + 20 + b2];
        }
        sWy[(ci * 3 + o) * 13 + f] = s;
    }
    if (t >= 128 && t < 245) {   // Wx: phantom out1-col (d=1 -> ox1=-1), b=4
        int q = t - 128;
        int ci = q / 39, o = (q % 39) / 13, e = q % 13;
        float s = 0.f;
#pragma unroll
        for (int c = 0; c < 5; ++c) {
            int a = e - 2 * c;
            if ((unsigned)a >= 5u) continue;
#pragma unroll
            for (int cm = 0; cm < 3; ++cm)
                s += sk1[ci * 75 + cm * 25 + c * 5 + 1] * sk2[cm * 75 + o * 25 + a * 5 + 4];
        }
        sWx[(ci * 3 + o) * 13 + e] = s;
    }
    if (t >= 246 && t < 255) {   // Wxy overlap
        int q = t - 246;
        int ci = q / 3, o = q % 3;
        float s = 0.f;
#pragma unroll
        for (int cm = 0; cm < 3; ++cm)
            s += sk1[ci * 75 + cm * 25 + 5 + 1] * sk2[cm * 75 + o * 25 + 20 + 4];
        sWxy[ci * 3 + o] = s;
    }
    __syncthreads();

    // ---- G: composite convT from prefetched taps, 256-thread split ----
    {
        float a0 = 0.f, a1 = 0.f, a2 = 0.f;
#pragma unroll
        for (int k = 0; k < 4; ++k) {
            if (k < nk) {
                int e = r0 + 4 * k;
#pragma unroll
                for (int lh = 0; lh < 2; ++lh) {
                    int l = h * 2 + lh;
                    if (l < nl) {
                        int f = f0 + 4 * l;
                        int wi = e * 13 + f;
                        float x0 = gx0[k][lh], x1 = gx1[k][lh], x2 = gx2[k][lh];
                        a0 += x0 * sW[wi]        + x1 * sW[507 + wi]  + x2 * sW[1014 + wi];
                        a1 += x0 * sW[169 + wi]  + x1 * sW[676 + wi]  + x2 * sW[1183 + wi];
                        a2 += x0 * sW[338 + wi]  + x1 * sW[845 + wi]  + x2 * sW[1352 + wi];
                    }
                }
            }
        }
        if (R == 0) {   // block 0 only: phantom-row correction, split by l
#pragma unroll
            for (int lh = 0; lh < 2; ++lh) {
                int l = h * 2 + lh;
                if (l < nl) {
                    int ix = xbase - l;
                    if ((unsigned)ix < 1024u) {
                        int f = f0 + 4 * l;
                        float x0 = 2.0f * in[ix] - 1.0f;
                        float x1 = 2.0f * in[1048576 + ix] - 1.0f;
                        float x2 = 2.0f * in[2097152 + ix] - 1.0f;
                        a0 -= x0 * sWy[f]      + x1 * sWy[39 + f] + x2 * sWy[78 + f];
                        a1 -= x0 * sWy[13 + f] + x1 * sWy[52 + f] + x2 * sWy[91 + f];
                        a2 -= x0 * sWy[26 + f] + x1 * sWy[65 + f] + x2 * sWy[104 + f];
                    }
                }
            }
        }
        if (C == 0 && h == 0) {   // j==0 threads only: phantom-col correction
#pragma unroll
            for (int k = 0; k < 4; ++k) {
                if (k < nk) {
                    int iy = ybase - k;
                    if ((unsigned)iy < 1024u) {
                        int e = r0 + 4 * k;
                        int off = iy * 1024;
                        float x0 = 2.0f * in[off] - 1.0f;
                        float x1 = 2.0f * in[1048576 + off] - 1.0f;
                        float x2 = 2.0f * in[2097152 + off] - 1.0f;
                        a0 -= x0 * sWx[e]      + x1 * sWx[39 + e] + x2 * sWx[78 + e];
                        a1 -= x0 * sWx[13 + e] + x1 * sWx[52 + e] + x2 * sWx[91 + e];
                        a2 -= x0 * sWx[26 + e] + x1 * sWx[65 + e] + x2 * sWx[104 + e];
                    }
                }
            }
        }
        if (R == 0 && C == 0 && h == 0) {
            float x0 = 2.0f * in[0] - 1.0f;
            float x1 = 2.0f * in[1048576] - 1.0f;
            float x2 = 2.0f * in[2097152] - 1.0f;
            a0 += x0 * sWxy[0] + x1 * sWxy[3] + x2 * sWxy[6];
            a1 += x0 * sWxy[1] + x1 * sWxy[4] + x2 * sWxy[7];
            a2 += x0 * sWxy[2] + x1 * sWxy[5] + x2 * sWxy[8];
        }
        if (h == 1) {
            sga[j] = a0; sga[128 + j] = a1; sga[256 + j] = a2;
        }
        __syncthreads();
        if (h == 0) {
            int T = blk * 128 + j;
            out[T]             = sigmoidf_(a0 + sga[j]);
            out[16384 + T]     = sigmoidf_(a1 + sga[128 + j]);
            out[2 * 16384 + T] = sigmoidf_(a2 + sga[256 + j]);
        }
    }
}

extern "C" void kernel_launch(void* const* d_in, const int* in_sizes, int n_in,
                              void* d_out, int out_size, void* d_ws, size_t ws_size,
                              hipStream_t stream) {
    const float* in   = (const float*)d_in[0];   // [3,1024,1024]
    const float* cw   = (const float*)d_in[1];   // [3,3,5,5]
    const float* cb   = (const float*)d_in[2];   // [3]
    const float* keys = (const float*)d_in[3];   // [100,3072]
    const float* vals = (const float*)d_in[4];   // [100,225]
    float* out = (float*)d_out;                  // [3,128,128] fp32

    unsigned* ctr = (unsigned*)d_ws;             // 2 barriers x 1KB (store-based)
    float* wsf = (float*)((char*)d_ws + 8192);   // float scratch: 2 x 16384 plog

    hipMemsetAsync(d_ws, 0, 2048, stream);       // zero barrier state
    k_fused<<<GRID, 256, 0, stream>>>(in, cw, cb, keys, vals, out, wsf, ctr);
}